// Round 4
// baseline (149.531 us; speedup 1.0000x reference)
//
#include <hip/hip_runtime.h>

#define DATA_BITS 108
#define SHIFT_BITS 7
#define F4_PER_ROW 27      // 108 floats = 27 float4; rows are 432B so row starts are 16B-aligned
#define RPT 256            // rows per tile == block threads

typedef float f32x4 __attribute__((ext_vector_type(4)));
typedef int   i32x4 __attribute__((ext_vector_type(4)));

// out[b][i] = (i + S[b] < 108) ? X[b][i + S[b]] : 0
// Branchless body: aligned lo/hi dwordx4 loads, OOB units clamp to the row's
// last already-fetched window, all tail elements zero-masked. Unrolled x9 for MLP.
__global__ __launch_bounds__(RPT) void barrel_fused_kernel(
    const float* __restrict__ X,
    const int* __restrict__ shift,
    float* __restrict__ out, int rows) {

    __shared__ int sRaw[RPT * SHIFT_BITS];   // 1792 ints = 7 KB
    __shared__ int sS[RPT];

    const int row0 = blockIdx.x * RPT;
    const int t = threadIdx.x;
    const int N = rows * DATA_BITS;          // 108,000,000 (fits int32)

    // ---- phase 1a: coalesced int4 staging of this block's shift bits into LDS
    const int total_sh = rows * SHIFT_BITS;
    const int base_sh  = row0 * SHIFT_BITS;
    #pragma unroll
    for (int kk = 0; kk < 2; ++kk) {
        const int li = (t + kk * RPT) * 4;           // LDS dword offset
        if (li < RPT * SHIFT_BITS) {
            const int gi = base_sh + li;
            if (gi + 4 <= total_sh) {
                *reinterpret_cast<i32x4*>(&sRaw[li]) =
                    *reinterpret_cast<const i32x4*>(&shift[gi]);
            } else {
                #pragma unroll
                for (int j = 0; j < 4; ++j)
                    sRaw[li + j] = (gi + j < total_sh) ? shift[gi + j] : 0;
            }
        }
    }
    __syncthreads();

    // ---- phase 1b: collapse 7 bits (layer 0 = MSB) -> sS
    {
        int s = 0;
        #pragma unroll
        for (int l = 0; l < SHIFT_BITS; ++l) s = (s << 1) | (sRaw[t * SHIFT_BITS + l] & 1);
        sS[t] = s;
    }
    __syncthreads();

    // ---- phase 2: branchless unit processing
    auto process = [&](int rb, int q) {
        const int s     = sS[rb];
        const int valid = DATA_BITS - s;             // may be <= 0 (s up to 127)
        const int i0    = q * 4;
        // clamp OOB units onto the row's last live lo-window (already fetched)
        const int i0e   = min(i0, max(valid - 1, 0) & ~3);
        const int rowbase = (row0 + rb) * DATA_BITS;
        int idx_lo = rowbase + i0e + (s & ~3);       // 16B-aligned
        idx_lo = min(idx_lo, N - 4);                 // final-row / dead-row clamp
        const int idx_hi = min(idx_lo + 4, N - 4);
        const f32x4 lo = *reinterpret_cast<const f32x4*>(X + idx_lo);
        const f32x4 hi = *reinterpret_cast<const f32x4*>(X + idx_hi);
        // branchless blend: rv[j] = w[(s&3) + j], w = {lo, hi}
        const int  m  = s & 3;
        const bool m2 = (m & 2) != 0;
        const bool m1 = (m & 1) != 0;
        const float t0 = m2 ? lo[2] : lo[0];
        const float t1 = m2 ? lo[3] : lo[1];
        const float t2 = m2 ? hi[0] : lo[2];
        const float t3 = m2 ? hi[1] : lo[3];
        const float t4 = m2 ? hi[2] : hi[0];
        f32x4 rv;
        rv[0] = m1 ? t1 : t0;
        rv[1] = m1 ? t2 : t1;
        rv[2] = m1 ? t3 : t2;
        rv[3] = m1 ? t4 : t3;
        // zero-mask src >= 108 tail (and whole dead rows)
        rv[0] = (i0 + 0 < valid) ? rv[0] : 0.f;
        rv[1] = (i0 + 1 < valid) ? rv[1] : 0.f;
        rv[2] = (i0 + 2 < valid) ? rv[2] : 0.f;
        rv[3] = (i0 + 3 < valid) ? rv[3] : 0.f;
        __builtin_nontemporal_store(rv,
            reinterpret_cast<f32x4*>(out + rowbase + i0));
    };

    const int nrows = min(RPT, rows - row0);
    if (nrows == RPT) {
        // full tile: exactly 27 units/thread; incremental rb/q (256 = 9*27 + 13)
        int rb = t / F4_PER_ROW;
        int q  = t - rb * F4_PER_ROW;
        #pragma unroll 9
        for (int k = 0; k < F4_PER_ROW; ++k) {
            process(rb, q);
            q  += 13;
            rb += 9;
            if (q >= F4_PER_ROW) { q -= F4_PER_ROW; rb += 1; }
        }
    } else {
        const int units = nrows * F4_PER_ROW;
        for (int u = t; u < units; u += RPT) {
            const int rb = u / F4_PER_ROW;
            const int q  = u - rb * F4_PER_ROW;
            process(rb, q);
        }
    }
}

extern "C" void kernel_launch(void* const* d_in, const int* in_sizes, int n_in,
                              void* d_out, int out_size, void* d_ws, size_t ws_size,
                              hipStream_t stream) {
    const float* X     = (const float*)d_in[0];
    const int*   shift = (const int*)d_in[1];
    float*       out   = (float*)d_out;

    const int rows = in_sizes[1] / SHIFT_BITS;              // 1,000,000
    const int grid = (rows + RPT - 1) / RPT;                // 3907

    barrel_fused_kernel<<<grid, RPT, 0, stream>>>(X, shift, out, rows);
}

// Round 5
// 148.485 us; speedup vs baseline: 1.0070x; 1.0070x over previous
//
#include <hip/hip_runtime.h>

#define DATA_BITS 108
#define SHIFT_BITS 7
#define F4_PER_ROW 27      // 108 floats = 27 float4; rows are 432B so row starts are 16B-aligned
#define RPT 256            // rows per tile == block threads

typedef float f32x4 __attribute__((ext_vector_type(4)));

// out[b][i] = (i + S[b] < 108) ? X[b][i + S[b]] : 0
// Branchless aligned lo/hi dwordx4 loads + 2-stage software pipeline:
// iteration k+1's loads are issued before iteration k's blend+store.
__global__ __launch_bounds__(RPT) void barrel_fused_kernel(
    const float* __restrict__ X,
    const int* __restrict__ shift,
    float* __restrict__ out, int rows) {

    __shared__ int sS[RPT];

    const int row0 = blockIdx.x * RPT;
    const int t = threadIdx.x;
    const int N = rows * DATA_BITS;          // 108,000,000 (fits int32)

    // ---- phase 1: collapse 7 shift bits (layer 0 = MSB) -> sS
    const int r = row0 + t;
    if (r < rows) {
        const int* p = shift + r * SHIFT_BITS;
        int s = 0;
        #pragma unroll
        for (int l = 0; l < SHIFT_BITS; ++l) s = (s << 1) | (p[l] & 1);
        sS[t] = s;
    }
    __syncthreads();

    struct U { int i0, valid, m, rowbase; };

    // address + metadata for unit u (branchless, always-loadable)
    auto prep = [&](int u, U& p) -> int {
        const int rb = u / F4_PER_ROW;               // constant divisor -> magic mul
        const int q  = u - rb * F4_PER_ROW;
        const int s  = sS[rb];
        p.valid   = DATA_BITS - s;                   // may be <= 0 (s up to 127)
        p.i0      = q * 4;
        p.m       = s & 3;
        p.rowbase = (row0 + rb) * DATA_BITS;
        // clamp OOB units onto the row's last live lo-window; dead rows -> row start
        const int i0e = min(p.i0, max(p.valid - 1, 0) & ~3);
        return min(p.rowbase + i0e + (s & ~3), N - 4);   // 16B-aligned
    };

    // blend + tail-mask + NT store for unit p given its lo/hi windows
    auto finish = [&](const U& p, f32x4 lo, f32x4 hi) {
        const bool m2 = (p.m & 2) != 0;
        const bool m1 = (p.m & 1) != 0;
        const float t0 = m2 ? lo[2] : lo[0];
        const float t1 = m2 ? lo[3] : lo[1];
        const float t2 = m2 ? hi[0] : lo[2];
        const float t3 = m2 ? hi[1] : lo[3];
        const float t4 = m2 ? hi[2] : hi[0];
        f32x4 rv;
        rv[0] = m1 ? t1 : t0;
        rv[1] = m1 ? t2 : t1;
        rv[2] = m1 ? t3 : t2;
        rv[3] = m1 ? t4 : t3;
        rv[0] = (p.i0 + 0 < p.valid) ? rv[0] : 0.f;  // zero-mask src >= 108 tail
        rv[1] = (p.i0 + 1 < p.valid) ? rv[1] : 0.f;  // (and whole dead rows)
        rv[2] = (p.i0 + 2 < p.valid) ? rv[2] : 0.f;
        rv[3] = (p.i0 + 3 < p.valid) ? rv[3] : 0.f;
        __builtin_nontemporal_store(rv,
            reinterpret_cast<f32x4*>(out + p.rowbase + p.i0));
    };

    const int nrows = min(RPT, rows - row0);
    if (nrows == RPT) {
        // full tile: exactly 27 units per thread, unit u = t + k*RPT
        U p0;
        int a0 = prep(t, p0);
        f32x4 lo0 = *reinterpret_cast<const f32x4*>(X + a0);
        f32x4 hi0 = *reinterpret_cast<const f32x4*>(X + min(a0 + 4, N - 4));
        #pragma unroll 1
        for (int k = 0; k < F4_PER_ROW; ++k) {
            U p1 = p0;
            f32x4 lo1 = lo0, hi1 = hi0;
            if (k + 1 < F4_PER_ROW) {               // issue next loads BEFORE this store
                const int a1 = prep(t + (k + 1) * RPT, p1);
                lo1 = *reinterpret_cast<const f32x4*>(X + a1);
                hi1 = *reinterpret_cast<const f32x4*>(X + min(a1 + 4, N - 4));
            }
            finish(p0, lo0, hi0);
            p0 = p1; lo0 = lo1; hi0 = hi1;
        }
    } else {
        // tail tile (last block, 64 rows): simple non-pipelined sweep
        const int units = nrows * F4_PER_ROW;
        for (int u = t; u < units; u += RPT) {
            U p;
            const int a = prep(u, p);
            const f32x4 lo = *reinterpret_cast<const f32x4*>(X + a);
            const f32x4 hi = *reinterpret_cast<const f32x4*>(X + min(a + 4, N - 4));
            finish(p, lo, hi);
        }
    }
}

extern "C" void kernel_launch(void* const* d_in, const int* in_sizes, int n_in,
                              void* d_out, int out_size, void* d_ws, size_t ws_size,
                              hipStream_t stream) {
    const float* X     = (const float*)d_in[0];
    const int*   shift = (const int*)d_in[1];
    float*       out   = (float*)d_out;

    const int rows = in_sizes[1] / SHIFT_BITS;              // 1,000,000
    const int grid = (rows + RPT - 1) / RPT;                // 3907

    barrel_fused_kernel<<<grid, RPT, 0, stream>>>(X, shift, out, rows);
}